// Round 3
// baseline (61.593 us; speedup 1.0000x reference)
//
#include <hip/hip_runtime.h>

// MoEBudgetAwareINLLayer: 5 iterations of
//   error  = x - mu
//   v_next = ALPHA*v - BETA*error          (v_cand == 0)
//   x_next = x + GATE*v_next
// Elementwise over B=8192, D=2048 f32. Traffic: 3 reads + 2 writes = 320 MiB
// -> ~53 us floor at 6.3 TB/s.
// R1: no-unroll grid-stride was latency-bound (VGPR=12) -> 66 us.
// R2: UNROLL=4 + NT stores -> 58.4 us (5.5 TB/s effective, ~87% of ceiling).
// R3: UNROLL=8 (24 loads in flight, VGPR ~64 keeps 8 waves/SIMD) to close
// the remaining latency gap.
//
// Inputs: d_in[0]=h (UNUSED), d_in[1]=x_init, d_in[2]=v_init, d_in[3]=mu,
// d_in[4]=default_iterations. Output: (x, v) concat: d_out[0:N]=x, [N:2N]=v.

#define ALPHA 0.5f
#define BETA  0.1f
#define GATE  0.9f
#define UNROLL 8

typedef float v4f __attribute__((ext_vector_type(4)));

__global__ __launch_bounds__(256) void inl_fused_kernel(
    const float4* __restrict__ x_init,
    const float4* __restrict__ v_init,
    const float4* __restrict__ mu,
    const int*    __restrict__ iters_p,
    float4* __restrict__ x_out,
    float4* __restrict__ v_out,
    int n_vec)
{
    const int iters = *iters_p;
    const int T = gridDim.x * blockDim.x;          // total threads
    int i = blockIdx.x * blockDim.x + threadIdx.x;

    // Main path: UNROLL float4s per thread, coalesced (lane-contiguous per k).
    for (; i + (UNROLL - 1) * T < n_vec; i += UNROLL * T) {
        float4 x4[UNROLL], v4[UNROLL], m4[UNROLL];
        #pragma unroll
        for (int k = 0; k < UNROLL; ++k) x4[k] = x_init[i + k * T];
        #pragma unroll
        for (int k = 0; k < UNROLL; ++k) v4[k] = v_init[i + k * T];
        #pragma unroll
        for (int k = 0; k < UNROLL; ++k) m4[k] = mu[i + k * T];

        for (int t = 0; t < iters; ++t) {
            #pragma unroll
            for (int k = 0; k < UNROLL; ++k) {
                float* x = reinterpret_cast<float*>(&x4[k]);
                float* v = reinterpret_cast<float*>(&v4[k]);
                float* m = reinterpret_cast<float*>(&m4[k]);
                #pragma unroll
                for (int c = 0; c < 4; ++c) {
                    float err = x[c] - m[c];
                    v[c] = ALPHA * v[c] - BETA * err;
                    x[c] = x[c] + GATE * v[c];
                }
            }
        }

        #pragma unroll
        for (int k = 0; k < UNROLL; ++k)
            __builtin_nontemporal_store(*(const v4f*)&x4[k], (v4f*)&x_out[i + k * T]);
        #pragma unroll
        for (int k = 0; k < UNROLL; ++k)
            __builtin_nontemporal_store(*(const v4f*)&v4[k], (v4f*)&v_out[i + k * T]);
    }

    // Tail (not taken for N=16.7M with exact grid, kept for generality).
    for (; i < n_vec; i += T) {
        float4 x4 = x_init[i];
        float4 v4 = v_init[i];
        float4 m4 = mu[i];
        float* x = reinterpret_cast<float*>(&x4);
        float* v = reinterpret_cast<float*>(&v4);
        float* m = reinterpret_cast<float*>(&m4);
        for (int t = 0; t < iters; ++t) {
            #pragma unroll
            for (int c = 0; c < 4; ++c) {
                float err = x[c] - m[c];
                v[c] = ALPHA * v[c] - BETA * err;
                x[c] = x[c] + GATE * v[c];
            }
        }
        __builtin_nontemporal_store(*(const v4f*)&x4, (v4f*)&x_out[i]);
        __builtin_nontemporal_store(*(const v4f*)&v4, (v4f*)&v_out[i]);
    }
}

extern "C" void kernel_launch(void* const* d_in, const int* in_sizes, int n_in,
                              void* d_out, int out_size, void* d_ws, size_t ws_size,
                              hipStream_t stream) {
    // d_in[0] = h (unused by reference)
    const float* x_init = (const float*)d_in[1];
    const float* v_init = (const float*)d_in[2];
    const float* mu     = (const float*)d_in[3];
    const int*   iters  = (const int*)d_in[4];

    const int n = in_sizes[1];          // B*D = 16,777,216
    float* x_out = (float*)d_out;
    float* v_out = x_out + (size_t)n;

    const int n_vec = n / 4;            // 4,194,304 float4s
    const int block = 256;
    int grid = (n_vec + block * UNROLL - 1) / (block * UNROLL);  // 2048: exact
    if (grid > 8192) grid = 8192;

    inl_fused_kernel<<<grid, block, 0, stream>>>(
        (const float4*)x_init, (const float4*)v_init, (const float4*)mu,
        iters, (float4*)x_out, (float4*)v_out, n_vec);
}

// Round 4
// 54.813 us; speedup vs baseline: 1.1237x; 1.1237x over previous
//
#include <hip/hip_runtime.h>

// MoEBudgetAwareINLLayer: iters steps of
//   error  = x - mu
//   v_next = ALPHA*v - BETA*error          (v_cand == 0)
//   x_next = x + GATE*v_next
// Elementwise over B=8192, D=2048 f32. Traffic: 3 reads + 2 writes = 320 MiB
// -> ~53 us floor at 6.3 TB/s.
// R1: no-unroll grid-stride, latency-bound (VGPR=12) -> 66.4 us.
// R2: UNROLL=4 + NT stores -> 58.4 us (5.5 TB/s effective, ~87% ceiling). BEST.
// R3: UNROLL=8 -> 61.6 us REGRESSION (VGPR=68, occupancy 60%->26%; ILP-for-TLP
//     trade lost). Reverting to UNROLL=4.
// R4: + closed-form: recurrence is linear, [e;v] <- M^iters [e0;v0] with
//     M = [[1-G*B, G*A], [-B, A]] (compile-time per step, powered at runtime
//     on uniform scalars). ~5 VALU ops/element instead of ~15.
//
// Inputs: d_in[0]=h (UNUSED), d_in[1]=x_init, d_in[2]=v_init, d_in[3]=mu,
// d_in[4]=default_iterations. Output: (x, v) concat: d_out[0:N]=x, [N:2N]=v.

#define ALPHA 0.5f
#define BETA  0.1f
#define GATE  0.9f
#define UNROLL 4

typedef float v4f __attribute__((ext_vector_type(4)));

__global__ __launch_bounds__(256) void inl_fused_kernel(
    const float4* __restrict__ x_init,
    const float4* __restrict__ v_init,
    const float4* __restrict__ mu,
    const int*    __restrict__ iters_p,
    float4* __restrict__ x_out,
    float4* __restrict__ v_out,
    int n_vec)
{
    const int iters = *iters_p;

    // Per-step transfer matrix on (e, v), e = x - mu:
    //   v' = -BETA*e + ALPHA*v
    //   e' = e + GATE*v' = (1 - GATE*BETA)*e + GATE*ALPHA*v
    // Power it `iters` times on uniform scalars (trivial cost, wave-uniform).
    float a = 1.f, b = 0.f, c = 0.f, d = 1.f;   // M^0
    for (int t = 0; t < iters; ++t) {
        const float m00 = 1.f - GATE * BETA, m01 = GATE * ALPHA;
        const float m10 = -BETA,             m11 = ALPHA;
        float na = m00 * a + m01 * c;
        float nb = m00 * b + m01 * d;
        float nc = m10 * a + m11 * c;
        float nd = m10 * b + m11 * d;
        a = na; b = nb; c = nc; d = nd;
    }
    // x_out = mu + a*e0 + b*v0 ; v_out = c*e0 + d*v0 ; e0 = x0 - mu.

    const int T = gridDim.x * blockDim.x;
    int i = blockIdx.x * blockDim.x + threadIdx.x;

    for (; i + (UNROLL - 1) * T < n_vec; i += UNROLL * T) {
        float4 x4[UNROLL], v4[UNROLL], m4[UNROLL];
        #pragma unroll
        for (int k = 0; k < UNROLL; ++k) x4[k] = x_init[i + k * T];
        #pragma unroll
        for (int k = 0; k < UNROLL; ++k) v4[k] = v_init[i + k * T];
        #pragma unroll
        for (int k = 0; k < UNROLL; ++k) m4[k] = mu[i + k * T];

        #pragma unroll
        for (int k = 0; k < UNROLL; ++k) {
            float* x = reinterpret_cast<float*>(&x4[k]);
            float* v = reinterpret_cast<float*>(&v4[k]);
            float* m = reinterpret_cast<float*>(&m4[k]);
            #pragma unroll
            for (int cc = 0; cc < 4; ++cc) {
                float e0 = x[cc] - m[cc];
                float v0 = v[cc];
                x[cc] = fmaf(a, e0, fmaf(b, v0, m[cc]));
                v[cc] = fmaf(c, e0, d * v0);
            }
        }

        #pragma unroll
        for (int k = 0; k < UNROLL; ++k)
            __builtin_nontemporal_store(*(const v4f*)&x4[k], (v4f*)&x_out[i + k * T]);
        #pragma unroll
        for (int k = 0; k < UNROLL; ++k)
            __builtin_nontemporal_store(*(const v4f*)&v4[k], (v4f*)&v_out[i + k * T]);
    }

    // Tail (not taken for N=16.7M with exact grid, kept for generality).
    for (; i < n_vec; i += T) {
        float4 x4 = x_init[i];
        float4 v4 = v_init[i];
        float4 m4 = mu[i];
        float* x = reinterpret_cast<float*>(&x4);
        float* v = reinterpret_cast<float*>(&v4);
        float* m = reinterpret_cast<float*>(&m4);
        #pragma unroll
        for (int cc = 0; cc < 4; ++cc) {
            float e0 = x[cc] - m[cc];
            float v0 = v[cc];
            x[cc] = fmaf(a, e0, fmaf(b, v0, m[cc]));
            v[cc] = fmaf(c, e0, d * v0);
        }
        __builtin_nontemporal_store(*(const v4f*)&x4, (v4f*)&x_out[i]);
        __builtin_nontemporal_store(*(const v4f*)&v4, (v4f*)&v_out[i]);
    }
}

extern "C" void kernel_launch(void* const* d_in, const int* in_sizes, int n_in,
                              void* d_out, int out_size, void* d_ws, size_t ws_size,
                              hipStream_t stream) {
    // d_in[0] = h (unused by reference)
    const float* x_init = (const float*)d_in[1];
    const float* v_init = (const float*)d_in[2];
    const float* mu     = (const float*)d_in[3];
    const int*   iters  = (const int*)d_in[4];

    const int n = in_sizes[1];          // B*D = 16,777,216
    float* x_out = (float*)d_out;
    float* v_out = x_out + (size_t)n;

    const int n_vec = n / 4;            // 4,194,304 float4s
    const int block = 256;
    int grid = (n_vec + block * UNROLL - 1) / (block * UNROLL);  // 4096: exact
    if (grid > 8192) grid = 8192;

    inl_fused_kernel<<<grid, block, 0, stream>>>(
        (const float4*)x_init, (const float4*)v_init, (const float4*)mu,
        iters, (float4*)x_out, (float4*)v_out, n_vec);
}